// Round 4
// baseline (17060.361 us; speedup 1.0000x reference)
//
#include <hip/hip_runtime.h>

#define B_   1024
#define S_   168
#define F_   64
#define H_   512
#define G4   2048
#define PRED 24
#define NWG  256
#define NTH  512

typedef unsigned short u16;
typedef unsigned int   u32;
typedef __attribute__((ext_vector_type(8))) __bf16 bf16x8;
typedef __attribute__((ext_vector_type(4))) float  f32x4;
typedef __attribute__((ext_vector_type(4))) int    i32x4;

__device__ __forceinline__ u16 f2bf(float f) {
  u32 u = __float_as_uint(f);
  u += 0x7fff + ((u >> 16) & 1);
  return (u16)(u >> 16);
}
__device__ __forceinline__ float bf2f(u16 h) { return __uint_as_float(((u32)h) << 16); }
__device__ __forceinline__ float sigm(float x) {
  x = fminf(fmaxf(x, -30.f), 30.f);
  return 1.f / (1.f + __expf(-x));
}
__device__ __forceinline__ float tanh_(float x) {
  x = fminf(fmaxf(x, -15.f), 15.f);
  float e = __expf(2.f * x);
  return (e - 1.f) / (e + 1.f);
}

// ---------------- prep kernels ----------------

// fp32 -> packed (hi | lo<<16) bf16 pair
__global__ void k_splitpack(const float* __restrict__ src, u32* __restrict__ dst, int n) {
  for (int i = blockIdx.x * 256 + threadIdx.x; i < n; i += gridDim.x * 256) {
    float a = src[i];
    u16 h = f2bf(a);
    u16 l = f2bf(a - bf2f(h));
    dst[i] = (u32)h | ((u32)l << 16);
  }
}

__global__ void k_w0c(const float* __restrict__ Wih0, const float* __restrict__ Wenc,
                      float* __restrict__ W0c) {
  int id = blockIdx.x * 256 + threadIdx.x;
  int j = id >> 6, f = id & 63;
  float s = 0.f;
  for (int i = 0; i < 128; ++i) s += Wih0[j * 128 + i] * Wenc[i * 64 + f];
  W0c[id] = s;
}

__global__ void k_w0cd(const float* __restrict__ W0c, const float* __restrict__ Wdec,
                       float* __restrict__ W0cd) {
  int id = blockIdx.x * 256 + threadIdx.x;
  int j = id >> 9, m = id & 511;
  float s = 0.f;
  for (int f = 0; f < 64; ++f) s += W0c[j * 64 + f] * Wdec[f * 512 + m];
  W0cd[id] = s;
}

__global__ void k_biases(const float* __restrict__ Wih0, const float* __restrict__ benc,
                         const float* __restrict__ bih0, const float* __restrict__ bhh0,
                         const float* __restrict__ bih1, const float* __restrict__ bhh1,
                         float* __restrict__ b0c, float* __restrict__ b1c) {
  int j = blockIdx.x * 256 + threadIdx.x;
  float s = 0.f;
  for (int i = 0; i < 128; ++i) s += Wih0[j * 128 + i] * benc[i];
  b0c[j] = s + bih0[j] + bhh0[j];
  b1c[j] = bih1[j] + bhh1[j];
}

__global__ void k_b0ar(const float* __restrict__ W0c, const float* __restrict__ bdec,
                       const float* __restrict__ b0c, float* __restrict__ b0ar) {
  int j = blockIdx.x * 256 + threadIdx.x;
  float s = 0.f;
  for (int f = 0; f < 64; ++f) s += W0c[j * 64 + f] * bdec[f];
  b0ar[j] = b0c[j] + s;
}

// Pack W [2048 x K] (row = g*512+j) into MFMA B-frag blocks: fi = (jt16*4+g)*NK+kt
// -> 2KB: [0,1KB)=hi, [1KB,2KB)=lo; within: lane*16B covers B[n=lane&15][k=(lane>>4)*8+e]
__global__ void k_pack(const float* __restrict__ W, int K, u16* __restrict__ dst) {
  int id = blockIdx.x * 256 + threadIdx.x;
  int lane = id & 63, fi = id >> 6;
  int NK = K >> 5;
  int kt = fi % NK, jg = fi / NK;
  int g = jg & 3, jt = jg >> 2;
  int j = jt * 16 + (lane & 15);
  int kb = kt * 32 + (lane >> 4) * 8;
  const float* src = W + (size_t)(g * 512 + j) * K + kb;
  u16 hi[8] __attribute__((aligned(16)));
  u16 lo[8] __attribute__((aligned(16)));
#pragma unroll
  for (int e = 0; e < 8; ++e) {
    float v = src[e];
    u16 h = f2bf(v);
    hi[e] = h;
    lo[e] = f2bf(v - bf2f(h));
  }
  u16* d = dst + (size_t)fi * 1024 + lane * 8;
  *(i32x4*)d = *(const i32x4*)hi;
  *(i32x4*)(d + 512) = *(const i32x4*)lo;
}

// ---------------- persistent cooperative LSTM kernel ----------------

struct Params {
  const u32* Xp;                 // [B][S][F] packed bf16 pair
  const u16 *W0cp, *W0cdp, *Whh0p, *Wih1p, *Whh1p;
  const float *b0c, *b0ar, *b1c;
  u32 *h0a, *h0b, *h1a, *h1b;    // packed h state (agent-scope transfers)
  float *c0, *c1;                // local-cached (same WG owns tile all steps)
  const float *Wdec, *bdec;
  float* out;
  u32* cnt;                      // monotonic grid-barrier counter
};

__global__ __launch_bounds__(NTH, 2) void lstm_persist(Params P) {
  __shared__ __align__(16) u32 smem_[24576];   // 96KB: 2x32KB packed A-stage; reused as reduce

  const int t = threadIdx.x;
  const int wg = blockIdx.x;
  const int jblk = wg & 15, mblk = wg >> 4;    // jblk fastest -> XCD = wg%8 keeps W L2-resident
  const int mbase = mblk * 64;
  const int lane = t & 63, wv = t >> 6;
  const int kk = wv >> 1, jh = wv & 1;         // 4-way K-split x 2 j-halves
  const int lr = lane & 15, qk = lane >> 4;
  const int jtg = jblk * 2 + jh;

  u32 v[16];
  i32x4 whA[4], wlA[4], whB[4], wlB[4];

  auto gbar = [&](int tgt) {
    __syncthreads();
    if (t == 0) {
      // RELEASE add: drains prior agent stores. RELAXED spin: no L2 invalidate -> W stays hot.
      __hip_atomic_fetch_add(P.cnt, 1u, __ATOMIC_RELEASE, __HIP_MEMORY_SCOPE_AGENT);
      while ((int)__hip_atomic_load(P.cnt, __ATOMIC_RELAXED, __HIP_MEMORY_SCOPE_AGENT) < tgt)
        __builtin_amdgcn_s_sleep(1);
    }
    __syncthreads();
  };

  auto layer_pass = [&](const u32* A1, int st1, int K1, const u16* W1p, bool a1u,
                        const u32* A2, const u16* W2p,
                        const float* bias, float* cmem, u32* hout) {
    const int nc1 = (K1 == 64) ? 1 : 4;
    const int NC  = nc1 + 4;
    const int NK1 = K1 >> 5;

    f32x4 acc[4][4];
#pragma unroll
    for (int mi = 0; mi < 4; ++mi)
#pragma unroll
      for (int g = 0; g < 4; ++g) acc[mi][g] = (f32x4){0.f, 0.f, 0.f, 0.f};

    auto chunkKc = [&](int cc) { return (cc < nc1 && K1 == 64) ? 64 : 128; };
    auto prmA = [&](int cc, const u32*& A, int& st, int& kb, bool& unc,
                    const u16*& Wp, int& NK) {
      if (cc < nc1) { A = A1; st = st1; kb = cc * 128; unc = a1u; Wp = W1p; NK = NK1; }
      else { A = A2; st = 512; kb = (cc - nc1) * 128; unc = true; Wp = W2p; NK = 16; }
    };

    auto stage_load = [&](int cc) {
      const u32* A; int st, kb; bool unc; const u16* Wp; int NK;
      prmA(cc, A, st, kb, unc, Wp, NK);
      if (chunkKc(cc) == 128) {
        int rb = t >> 7, col = t & 127;
        const u32* base = A + (size_t)(mbase + rb) * st + kb + col;
        if (unc) {
#pragma unroll
          for (int i = 0; i < 16; ++i)
            v[i] = __hip_atomic_load(base + (size_t)i * 4 * st, __ATOMIC_RELAXED,
                                     __HIP_MEMORY_SCOPE_AGENT);
        } else {
#pragma unroll
          for (int i = 0; i < 16; ++i) v[i] = base[(size_t)i * 4 * st];
        }
      } else {
        int rb = t >> 6, col = t & 63;
        const u32* base = A + (size_t)(mbase + rb) * st + kb + col;
        if (unc) {
#pragma unroll
          for (int i = 0; i < 8; ++i)
            v[i] = __hip_atomic_load(base + (size_t)i * 8 * st, __ATOMIC_RELAXED,
                                     __HIP_MEMORY_SCOPE_AGENT);
        } else {
#pragma unroll
          for (int i = 0; i < 8; ++i) v[i] = base[(size_t)i * 8 * st];
        }
      }
    };

    auto stage_write = [&](int cc, int buf) {
      u32* sb = smem_ + buf * 8192;
      if (chunkKc(cc) == 128) {
        int rb = t >> 7, col = t & 127;
        int pcol = col >> 3, e = col & 7;
#pragma unroll
        for (int i = 0; i < 16; ++i) {
          int row = i * 4 + rb;
          sb[row * 128 + (pcol ^ (row & 15)) * 8 + e] = v[i];
        }
      } else {
        int rb = t >> 6, col = t & 63;
        int pcol = col >> 3, e = col & 7;
#pragma unroll
        for (int i = 0; i < 8; ++i) {
          int row = i * 8 + rb;
          sb[row * 64 + (pcol ^ (row & 7)) * 8 + e] = v[i];
        }
      }
    };

    auto loadW = [&](const u16* Wp, int NK, int kt, i32x4* wh, i32x4* wl) {
#pragma unroll
      for (int g = 0; g < 4; ++g) {
        const u16* p_ = Wp + (size_t)((jtg * 4 + g) * NK + kt) * 1024 + lane * 8;
        wh[g] = *(const i32x4*)p_;
        wl[g] = *(const i32x4*)(p_ + 512);
      }
    };

    auto mstep = [&](int buf, int Kc) {
      const u32* sb = smem_ + buf * 8192;
      const int pm = (Kc >> 3) - 1;
      bf16x8 ah[4], al[4];
#pragma unroll
      for (int mi = 0; mi < 4; ++mi) {
        int rowA = mi * 16 + lr;
        int pw = (kk * 4 + qk) ^ (rowA & pm);
        const u32* pp_ = sb + rowA * Kc + pw * 8;
        i32x4 d0 = *(const i32x4*)pp_;
        i32x4 d1 = *(const i32x4*)(pp_ + 4);
        // unpack packed (hi|lo<<16): hi = low halves, lo = high halves
        i32x4 hv = { (int)__builtin_amdgcn_perm((u32)d0[1], (u32)d0[0], 0x05040100),
                     (int)__builtin_amdgcn_perm((u32)d0[3], (u32)d0[2], 0x05040100),
                     (int)__builtin_amdgcn_perm((u32)d1[1], (u32)d1[0], 0x05040100),
                     (int)__builtin_amdgcn_perm((u32)d1[3], (u32)d1[2], 0x05040100) };
        i32x4 lv = { (int)__builtin_amdgcn_perm((u32)d0[1], (u32)d0[0], 0x07060302),
                     (int)__builtin_amdgcn_perm((u32)d0[3], (u32)d0[2], 0x07060302),
                     (int)__builtin_amdgcn_perm((u32)d1[1], (u32)d1[0], 0x07060302),
                     (int)__builtin_amdgcn_perm((u32)d1[3], (u32)d1[2], 0x07060302) };
        ah[mi] = __builtin_bit_cast(bf16x8, hv);
        al[mi] = __builtin_bit_cast(bf16x8, lv);
      }
#pragma unroll
      for (int g = 0; g < 4; ++g) {
        bf16x8 bh = __builtin_bit_cast(bf16x8, whA[g]);
        bf16x8 bl = __builtin_bit_cast(bf16x8, wlA[g]);
#pragma unroll
        for (int mi = 0; mi < 4; ++mi) {
          acc[mi][g] = __builtin_amdgcn_mfma_f32_16x16x32_bf16(ah[mi], bh, acc[mi][g], 0, 0, 0);
          acc[mi][g] = __builtin_amdgcn_mfma_f32_16x16x32_bf16(al[mi], bh, acc[mi][g], 0, 0, 0);
          acc[mi][g] = __builtin_amdgcn_mfma_f32_16x16x32_bf16(ah[mi], bl, acc[mi][g], 0, 0, 0);
        }
      }
    };

    stage_load(0);
    stage_write(0, 0);
    {
      const u32* A; int st, kb; bool unc; const u16* Wp; int NK;
      prmA(0, A, st, kb, unc, Wp, NK);
      if (kk < (chunkKc(0) >> 5)) loadW(Wp, NK, (kb >> 5) + kk, whA, wlA);
    }
    __syncthreads();

    for (int cc = 0; cc < NC; ++cc) {
      int buf = cc & 1;
      bool more = cc + 1 < NC;
      if (more) {
        stage_load(cc + 1);
        const u32* A; int st, kb; bool unc; const u16* Wp; int NK;
        prmA(cc + 1, A, st, kb, unc, Wp, NK);
        if (kk < (chunkKc(cc + 1) >> 5)) loadW(Wp, NK, (kb >> 5) + kk, whB, wlB);
      }
      if (kk < (chunkKc(cc) >> 5)) mstep(buf, chunkKc(cc));
      if (more) stage_write(cc + 1, buf ^ 1);
      __syncthreads();
      if (more) {
#pragma unroll
        for (int g = 0; g < 4; ++g) { whA[g] = whB[g]; wlA[g] = wlB[g]; }
      }
    }

    // 4-way K-split reduction through LDS (region: [(jh*4+mi)*3+slot] x 4KB)
    float* red = (float*)smem_;
#pragma unroll
    for (int mi = 0; mi < 4; ++mi) {
      if (mi != kk) {
        int slot = kk - (kk > mi ? 1 : 0);
        float* base = red + (size_t)(((jh * 4 + mi) * 3 + slot) * 1024) + lane * 4;
#pragma unroll
        for (int g = 0; g < 4; ++g) *(f32x4*)(base + g * 256) = acc[mi][g];
      }
    }
    __syncthreads();

    f32x4 r[4];
#pragma unroll
    for (int g = 0; g < 4; ++g) r[g] = acc[0][g];
    if (kk == 1) {
#pragma unroll
      for (int g = 0; g < 4; ++g) r[g] = acc[1][g];
    } else if (kk == 2) {
#pragma unroll
      for (int g = 0; g < 4; ++g) r[g] = acc[2][g];
    } else if (kk == 3) {
#pragma unroll
      for (int g = 0; g < 4; ++g) r[g] = acc[3][g];
    }
#pragma unroll
    for (int sl = 0; sl < 3; ++sl) {
      float* base = red + (size_t)(((jh * 4 + kk) * 3 + sl) * 1024) + lane * 4;
#pragma unroll
      for (int g = 0; g < 4; ++g) r[g] += *(const f32x4*)(base + g * 256);
    }

    // epilogue: C/D col = lane&15 -> j, row = qk*4+rr -> batch [m89/m91-verified]
    const int   j   = jblk * 32 + jh * 16 + lr;
    const float bi  = bias[j];
    const float bff = bias[512 + j];
    const float bg  = bias[1024 + j];
    const float bo  = bias[1536 + j];
#pragma unroll
    for (int rr = 0; rr < 4; ++rr) {
      int b   = mbase + kk * 16 + qk * 4 + rr;
      int idx = b * 512 + j;
      float iv = sigm(r[0][rr] + bi);
      float fv = sigm(r[1][rr] + bff);
      float gv = tanh_(r[2][rr] + bg);
      float ov = sigm(r[3][rr] + bo);
      float cn = fv * cmem[idx] + iv * gv;
      cmem[idx] = cn;
      float hn = ov * tanh_(cn);
      u16 hh = f2bf(hn);
      u16 hl = f2bf(hn - bf2f(hh));
      u32 hp = (u32)hh | ((u32)hl << 16);
      __hip_atomic_store(&hout[idx], hp, __ATOMIC_RELAXED, __HIP_MEMORY_SCOPE_AGENT);
    }
  };

  int target = 0;
  u32 *h0r = P.h0a, *h0w = P.h0b, *h1r = P.h1a, *h1w = P.h1b;

  for (int s = 0; s < S_ + PRED - 1; ++s) {
    // ---- layer 0 ----
    if (s < S_)
      layer_pass(P.Xp + (size_t)s * F_, S_ * F_, 64, P.W0cp, false,
                 h0r, P.Whh0p, P.b0c, P.c0, h0w);
    else
      layer_pass(h1r, 512, 512, P.W0cdp, true,
                 h0r, P.Whh0p, P.b0ar, P.c0, h0w);
    gbar(target += NWG);

    // ---- layer 1 ----
    layer_pass(h0w, 512, 512, P.Wih1p, true,
               h1r, P.Whh1p, P.b1c, P.c1, h1w);
    gbar(target += NWG);

    // ---- decoder (piggybacked; h1w safe until layer1 of step s+2) ----
    if (s >= S_ - 1) {
      float* outp = P.out + (size_t)(s - (S_ - 1)) * F_;
      int bb = mblk * 64 + (t >> 3);
      int k0 = jblk * 32;
      int f0 = (t & 7) * 8;
      float a[8];
#pragma unroll
      for (int ff = 0; ff < 8; ++ff) a[ff] = 0.f;
      for (int k = 0; k < 32; ++k) {
        u32 pk = __hip_atomic_load(&h1w[(size_t)bb * 512 + k0 + k], __ATOMIC_RELAXED,
                                   __HIP_MEMORY_SCOPE_AGENT);
        float hv = bf2f((u16)(pk & 0xffffu)) + bf2f((u16)(pk >> 16));
#pragma unroll
        for (int ff = 0; ff < 8; ++ff)
          a[ff] += hv * P.Wdec[(f0 + ff) * 512 + k0 + k];
      }
#pragma unroll
      for (int ff = 0; ff < 8; ++ff) {
        float vv = a[ff];
        if (k0 == 0) vv += P.bdec[f0 + ff];
        atomicAdd(&outp[(size_t)bb * (PRED * F_) + f0 + ff], vv);
      }
    }

    u32* tmp;
    tmp = h0r; h0r = h0w; h0w = tmp;
    tmp = h1r; h1r = h1w; h1w = tmp;
  }
}

// ---------------- host orchestration ----------------

extern "C" void kernel_launch(void* const* d_in, const int* in_sizes, int n_in,
                              void* d_out, int out_size, void* d_ws, size_t ws_size,
                              hipStream_t stream) {
  const float* x    = (const float*)d_in[0];
  const float* Wenc = (const float*)d_in[1];
  const float* benc = (const float*)d_in[2];
  const float* Wih0 = (const float*)d_in[3];
  const float* Whh0 = (const float*)d_in[4];
  const float* bih0 = (const float*)d_in[5];
  const float* bhh0 = (const float*)d_in[6];
  const float* Wih1 = (const float*)d_in[7];
  const float* Whh1 = (const float*)d_in[8];
  const float* bih1 = (const float*)d_in[9];
  const float* bhh1 = (const float*)d_in[10];
  const float* Wdec = (const float*)d_in[11];
  const float* bdec = (const float*)d_in[12];

  char* p = (char*)d_ws;
  auto carve = [&](size_t bytes) { char* r = p; p += (bytes + 255) & ~(size_t)255; return r; };
  const size_t NX = (size_t)B_ * S_ * F_;
  const size_t NH = (size_t)B_ * H_;
  const size_t WPK = (size_t)G4 * 512 * 2 * 2;   // packed K=512 W bytes (hi+lo)
  u32* Xp     = (u32*)carve(NX * 4);
  float* W0c  = (float*)carve((size_t)G4 * 64 * 4);
  float* W0cd = (float*)carve((size_t)G4 * 512 * 4);
  u16* W0cp   = (u16*)carve((size_t)G4 * 64 * 2 * 2);
  u16* W0cdp  = (u16*)carve(WPK);
  u16* Whh0p  = (u16*)carve(WPK);
  u16* Wih1p  = (u16*)carve(WPK);
  u16* Whh1p  = (u16*)carve(WPK);
  float* b0c  = (float*)carve(G4 * 4);
  float* b0ar = (float*)carve(G4 * 4);
  float* b1c  = (float*)carve(G4 * 4);
  u32* h0a = (u32*)carve(NH * 4);
  u32* h0b = (u32*)carve(NH * 4);
  u32* h1a = (u32*)carve(NH * 4);
  u32* h1b = (u32*)carve(NH * 4);
  float* c0 = (float*)carve(NH * 4);
  float* c1 = (float*)carve(NH * 4);
  u32* cnt  = (u32*)carve(256);
  (void)ws_size; (void)n_in; (void)in_sizes;

  hipMemsetAsync(d_out, 0, (size_t)out_size * 4, stream);
  hipMemsetAsync(h0a, 0, NH * 4, stream);
  hipMemsetAsync(h1a, 0, NH * 4, stream);
  hipMemsetAsync(c0, 0, NH * 4, stream);
  hipMemsetAsync(c1, 0, NH * 4, stream);
  hipMemsetAsync(cnt, 0, 256, stream);

  k_splitpack<<<4096, 256, 0, stream>>>(x, Xp, (int)NX);
  k_w0c<<<512, 256, 0, stream>>>(Wih0, Wenc, W0c);
  k_w0cd<<<4096, 256, 0, stream>>>(W0c, Wdec, W0cd);
  k_biases<<<8, 256, 0, stream>>>(Wih0, benc, bih0, bhh0, bih1, bhh1, b0c, b1c);
  k_b0ar<<<8, 256, 0, stream>>>(W0c, bdec, b0c, b0ar);
  k_pack<<<32 * 16, 256, 0, stream>>>(Whh0, 512, Whh0p);
  k_pack<<<32 * 16, 256, 0, stream>>>(Wih1, 512, Wih1p);
  k_pack<<<32 * 16, 256, 0, stream>>>(Whh1, 512, Whh1p);
  k_pack<<<32 * 16, 256, 0, stream>>>(W0cd, 512, W0cdp);
  k_pack<<<32 * 2, 256, 0, stream>>>(W0c, 64, W0cp);

  Params prm;
  prm.Xp = Xp;
  prm.W0cp = W0cp; prm.W0cdp = W0cdp; prm.Whh0p = Whh0p;
  prm.Wih1p = Wih1p; prm.Whh1p = Whh1p;
  prm.b0c = b0c; prm.b0ar = b0ar; prm.b1c = b1c;
  prm.h0a = h0a; prm.h0b = h0b; prm.h1a = h1a; prm.h1b = h1b;
  prm.c0 = c0; prm.c1 = c1;
  prm.Wdec = Wdec; prm.bdec = bdec;
  prm.out = (float*)d_out;
  prm.cnt = cnt;

  void* kargs[] = { &prm };
  hipLaunchCooperativeKernel(reinterpret_cast<void*>(lstm_persist),
                             dim3(NWG), dim3(NTH), kargs, 0, stream);
}

// Round 7
// 9625.290 us; speedup vs baseline: 1.7725x; 1.7725x over previous
//
#include <hip/hip_runtime.h>

#define B_   1024
#define S_   168
#define F_   64
#define H_   512
#define G4   2048
#define PRED 24
#define NWG  256
#define NTH  512

typedef unsigned short u16;
typedef unsigned int   u32;
typedef __attribute__((ext_vector_type(8))) __bf16 bf16x8;
typedef __attribute__((ext_vector_type(4))) float  f32x4;
typedef __attribute__((ext_vector_type(4))) int    i32x4;

__device__ __forceinline__ u16 f2bf(float f) {
  u32 u = __float_as_uint(f);
  u += 0x7fff + ((u >> 16) & 1);
  return (u16)(u >> 16);
}
__device__ __forceinline__ float bf2f(u16 h) { return __uint_as_float(((u32)h) << 16); }
__device__ __forceinline__ float sigm(float x) {
  x = fminf(fmaxf(x, -30.f), 30.f);
  return 1.f / (1.f + __expf(-x));
}
__device__ __forceinline__ float tanh_(float x) {
  x = fminf(fmaxf(x, -15.f), 15.f);
  float e = __expf(2.f * x);
  return (e - 1.f) / (e + 1.f);
}

// FUSED sc0 loads + wait in ONE asm block: results are architecturally valid at
// asm exit (no async-register hazard; =&v prevents result/address aliasing).
// sc0 = L1-bypass, serves from the local (per-XCD) L2.
__device__ __forceinline__ void load2_sc0_wait(i32x4& d0, i32x4& d1,
                                               const u32* p0, const u32* p1) {
  asm volatile(
      "global_load_dwordx4 %0, %2, off sc0\n\t"
      "global_load_dwordx4 %1, %3, off sc0\n\t"
      "s_waitcnt vmcnt(0)"
      : "=&v"(d0), "=&v"(d1)
      : "v"(p0), "v"(p1)
      : "memory");
}
__device__ __forceinline__ void load4_sc0_wait(i32x4& d0, i32x4& d1, i32x4& d2, i32x4& d3,
                                               const u32* p0, const u32* p1,
                                               const u32* p2, const u32* p3) {
  asm volatile(
      "global_load_dwordx4 %0, %4, off sc0\n\t"
      "global_load_dwordx4 %1, %5, off sc0\n\t"
      "global_load_dwordx4 %2, %6, off sc0\n\t"
      "global_load_dwordx4 %3, %7, off sc0\n\t"
      "s_waitcnt vmcnt(0)"
      : "=&v"(d0), "=&v"(d1), "=&v"(d2), "=&v"(d3)
      : "v"(p0), "v"(p1), "v"(p2), "v"(p3)
      : "memory");
}
__device__ __forceinline__ void load8_sc0_wait(i32x4* d, const u32* p) {
  asm volatile(
      "global_load_dwordx4 %0, %8, off sc0\n\t"
      "global_load_dwordx4 %1, %9, off sc0\n\t"
      "global_load_dwordx4 %2, %10, off sc0\n\t"
      "global_load_dwordx4 %3, %11, off sc0\n\t"
      "global_load_dwordx4 %4, %12, off sc0\n\t"
      "global_load_dwordx4 %5, %13, off sc0\n\t"
      "global_load_dwordx4 %6, %14, off sc0\n\t"
      "global_load_dwordx4 %7, %15, off sc0\n\t"
      "s_waitcnt vmcnt(0)"
      : "=&v"(d[0]), "=&v"(d[1]), "=&v"(d[2]), "=&v"(d[3]),
        "=&v"(d[4]), "=&v"(d[5]), "=&v"(d[6]), "=&v"(d[7])
      : "v"(p), "v"(p + 4), "v"(p + 8), "v"(p + 12),
        "v"(p + 16), "v"(p + 20), "v"(p + 24), "v"(p + 28)
      : "memory");
}

// ---------------- prep kernels ----------------

__global__ void k_splitpack(const float* __restrict__ src, u32* __restrict__ dst, int n) {
  for (int i = blockIdx.x * 256 + threadIdx.x; i < n; i += gridDim.x * 256) {
    float a = src[i];
    u16 h = f2bf(a);
    u16 l = f2bf(a - bf2f(h));
    dst[i] = (u32)h | ((u32)l << 16);
  }
}

__global__ void k_w0c(const float* __restrict__ Wih0, const float* __restrict__ Wenc,
                      float* __restrict__ W0c) {
  int id = blockIdx.x * 256 + threadIdx.x;
  int j = id >> 6, f = id & 63;
  float s = 0.f;
  for (int i = 0; i < 128; ++i) s += Wih0[j * 128 + i] * Wenc[i * 64 + f];
  W0c[id] = s;
}

__global__ void k_w0cd(const float* __restrict__ W0c, const float* __restrict__ Wdec,
                       float* __restrict__ W0cd) {
  int id = blockIdx.x * 256 + threadIdx.x;
  int j = id >> 9, m = id & 511;
  float s = 0.f;
  for (int f = 0; f < 64; ++f) s += W0c[j * 64 + f] * Wdec[f * 512 + m];
  W0cd[id] = s;
}

__global__ void k_biases(const float* __restrict__ Wih0, const float* __restrict__ benc,
                         const float* __restrict__ bih0, const float* __restrict__ bhh0,
                         const float* __restrict__ bih1, const float* __restrict__ bhh1,
                         float* __restrict__ b0c, float* __restrict__ b1c) {
  int j = blockIdx.x * 256 + threadIdx.x;
  float s = 0.f;
  for (int i = 0; i < 128; ++i) s += Wih0[j * 128 + i] * benc[i];
  b0c[j] = s + bih0[j] + bhh0[j];
  b1c[j] = bih1[j] + bhh1[j];
}

__global__ void k_b0ar(const float* __restrict__ W0c, const float* __restrict__ bdec,
                       const float* __restrict__ b0c, float* __restrict__ b0ar) {
  int j = blockIdx.x * 256 + threadIdx.x;
  float s = 0.f;
  for (int f = 0; f < 64; ++f) s += W0c[j * 64 + f] * bdec[f];
  b0ar[j] = b0c[j] + s;
}

// Pack W [2048 x K] (row = g*512+j) into MFMA B-frag blocks: fi = (jt16*4+g)*NK+kt
// -> 2KB: [0,1KB)=hi, [1KB,2KB)=lo; lane*16B covers B[n=lane&15][k=(lane>>4)*8+e]
__global__ void k_pack(const float* __restrict__ W, int K, u16* __restrict__ dst) {
  int id = blockIdx.x * 256 + threadIdx.x;
  int lane = id & 63, fi = id >> 6;
  int NK = K >> 5;
  int kt = fi % NK, jg = fi / NK;
  int g = jg & 3, jt = jg >> 2;
  int j = jt * 16 + (lane & 15);
  int kb = kt * 32 + (lane >> 4) * 8;
  const float* src = W + (size_t)(g * 512 + j) * K + kb;
  u16 hi[8] __attribute__((aligned(16)));
  u16 lo[8] __attribute__((aligned(16)));
#pragma unroll
  for (int e = 0; e < 8; ++e) {
    float v = src[e];
    u16 h = f2bf(v);
    hi[e] = h;
    lo[e] = f2bf(v - bf2f(h));
  }
  u16* d = dst + (size_t)fi * 1024 + lane * 8;
  *(i32x4*)d = *(const i32x4*)hi;
  *(i32x4*)(d + 512) = *(const i32x4*)lo;
}

// ---------------- persistent cooperative LSTM kernel ----------------

struct Params {
  const u32* Xp;
  const u16 *W0cp, *W0cdp, *Whh0p, *Wih1p, *Whh1p;
  const float *b0c, *b0ar, *b1c;
  u32 *h0a, *h0b, *h1a, *h1b;    // packed h; XCD-local: write-through stores + sc0 loads
  float *c0, *c1;                // WG-private
  const float *Wdec, *bdec;
  float* out;
  u32* xcdctr;                   // 8 slot counters (x64 stride)
  u32* cnt8;                     // 8 per-XCD barrier counters (x64 stride)
};

__global__ __launch_bounds__(NTH, 2) void lstm_persist(Params P) {
  __shared__ __align__(16) u32 smem_[24576];   // 96KB -> hard 1 WG/CU
  __shared__ int s_xcd, s_slot;

  const int t = threadIdx.x;
  // Self-organize by PHYSICAL XCD: 96KB LDS => 1 WG/CU; 256 co-resident WGs on
  // 256 CUs => pigeonhole: exactly 32 WGs per XCD, any dispatch policy. All h/c
  // dataflow is m-sliced, so putting m-tiles {xcd, xcd+8} on their physical XCD
  // makes every h transfer same-L2 (write-through stores + sc0 loads).
  if (t == 0) {
    u32 xcc;
    asm volatile("s_getreg_b32 %0, hwreg(HW_REG_XCC_ID)" : "=s"(xcc));
    xcc &= 7;
    s_xcd = (int)xcc;
    s_slot = (int)__hip_atomic_fetch_add(P.xcdctr + xcc * 64, 1u,
                                         __ATOMIC_RELAXED, __HIP_MEMORY_SCOPE_AGENT);
  }
  __syncthreads();
  const int xcd  = s_xcd;
  const int slot = s_slot;
  const int jblk = slot & 15;
  const int mblk = xcd + 8 * ((slot >> 4) & 1);
  const int mbase = mblk * 64;
  u32* const cntp = P.cnt8 + xcd * 64;

  const int lane = t & 63, wv = t >> 6;
  const int kk = wv >> 1, jh = wv & 1;
  const int lr = lane & 15, qk = lane >> 4;
  const int jtg = jblk * 2 + jh;

  i32x4 whA[4], wlA[4], whB[4], wlB[4];

  // Per-XCD barrier (32 arrivals). __syncthreads drains all waves' stores to L2
  // before arrival; counter RMW/spin at agent scope (L3) — R4-proven mechanism —
  // never invalidates the local L2, so W and h lines stay hot.
  auto gbar = [&](int tgt) {
    __syncthreads();
    if (t == 0) {
      __hip_atomic_fetch_add(cntp, 1u, __ATOMIC_RELAXED, __HIP_MEMORY_SCOPE_AGENT);
      while ((int)__hip_atomic_load(cntp, __ATOMIC_RELAXED, __HIP_MEMORY_SCOPE_AGENT) < tgt)
        __builtin_amdgcn_s_sleep(1);
    }
    __syncthreads();
  };

  auto layer_pass = [&](const u32* A1, int st1, int K1, bool a1_is_h, const u16* W1p,
                        const u32* A2, const u16* W2p,
                        const float* bias, float* cmem, u32* hout) {
    const int nc1 = (K1 == 64) ? 1 : 4;
    const int NC  = nc1 + 4;
    const int NK1 = K1 >> 5;

    f32x4 acc[4][4];
#pragma unroll
    for (int mi = 0; mi < 4; ++mi)
#pragma unroll
      for (int g = 0; g < 4; ++g) acc[mi][g] = (f32x4){0.f, 0.f, 0.f, 0.f};

    auto isK64 = [&](int cc) { return cc < nc1 && K1 == 64; };
    auto prmA = [&](int cc, const u32*& A, int& st, int& kb, bool& ish,
                    const u16*& Wp, int& NK) {
      if (cc < nc1) { A = A1; st = st1; kb = cc * 128; ish = a1_is_h; Wp = W1p; NK = NK1; }
      else { A = A2; st = 512; kb = (cc - nc1) * 128; ish = true; Wp = W2p; NK = 16; }
    };

    // stage: load A chunk (fused sc0+wait for h, plain cached for X) then write
    // LDS with the 32B-piece XOR swizzle. Values are valid C++ values here.
    auto stage = [&](int cc, int buf) {
      const u32* A; int st, kb; bool ish; const u16* Wp; int NK;
      prmA(cc, A, st, kb, ish, Wp, NK);
      u32* sb = smem_ + buf * 8192;
      if (!isK64(cc)) {                       // Kc=128: 64 rows x 512B
        int row0 = t >> 5, qcol = t & 31;
        const u32* src = A + (size_t)(mbase + row0) * st + kb + qcol * 4;
        i32x4 sv0, sv1, sv2, sv3;
        if (ish) {
          load4_sc0_wait(sv0, sv1, sv2, sv3,
                         src, src + (size_t)16 * st,
                         src + (size_t)32 * st, src + (size_t)48 * st);
        } else {
          sv0 = *(const i32x4*)src;
          sv1 = *(const i32x4*)(src + (size_t)16 * st);
          sv2 = *(const i32x4*)(src + (size_t)32 * st);
          sv3 = *(const i32x4*)(src + (size_t)48 * st);
        }
        int pc = qcol >> 1, half = (qcol & 1) * 4;
        int row = row0;
        *(i32x4*)&sb[row * 128 + (pc ^ (row & 15)) * 8 + half] = sv0;
        row = row0 + 16;
        *(i32x4*)&sb[row * 128 + (pc ^ (row & 15)) * 8 + half] = sv1;
        row = row0 + 32;
        *(i32x4*)&sb[row * 128 + (pc ^ (row & 15)) * 8 + half] = sv2;
        row = row0 + 48;
        *(i32x4*)&sb[row * 128 + (pc ^ (row & 15)) * 8 + half] = sv3;
      } else {                                // Kc=64 (TF X chunk, never h)
        int row0 = t >> 4, qcol = t & 15;
        const u32* src = A + (size_t)(mbase + row0) * st + kb + qcol * 4;
        i32x4 sv0 = *(const i32x4*)src;
        i32x4 sv1 = *(const i32x4*)(src + (size_t)32 * st);
        int pc = qcol >> 1, half = (qcol & 1) * 4;
        int row = row0;
        *(i32x4*)&sb[row * 64 + (pc ^ (row & 7)) * 8 + half] = sv0;
        row = row0 + 32;
        *(i32x4*)&sb[row * 64 + (pc ^ (row & 7)) * 8 + half] = sv1;
      }
    };

    auto loadW = [&](const u16* Wp, int NK, int kt, i32x4* wh, i32x4* wl) {
#pragma unroll
      for (int g = 0; g < 4; ++g) {
        const u16* p_ = Wp + (size_t)((jtg * 4 + g) * NK + kt) * 1024 + lane * 8;
        wh[g] = *(const i32x4*)p_;
        wl[g] = *(const i32x4*)(p_ + 512);
      }
    };

    auto mstep = [&](int buf, int Kc) {
      const u32* sb = smem_ + buf * 8192;
      const int pm = (Kc >> 3) - 1;
      bf16x8 ah[4], al[4];
#pragma unroll
      for (int mi = 0; mi < 4; ++mi) {
        int rowA = mi * 16 + lr;
        int pw = (kk * 4 + qk) ^ (rowA & pm);
        const u32* pp_ = sb + rowA * Kc + pw * 8;
        i32x4 d0 = *(const i32x4*)pp_;
        i32x4 d1 = *(const i32x4*)(pp_ + 4);
        i32x4 hv = { (int)__builtin_amdgcn_perm((u32)d0[1], (u32)d0[0], 0x05040100),
                     (int)__builtin_amdgcn_perm((u32)d0[3], (u32)d0[2], 0x05040100),
                     (int)__builtin_amdgcn_perm((u32)d1[1], (u32)d1[0], 0x05040100),
                     (int)__builtin_amdgcn_perm((u32)d1[3], (u32)d1[2], 0x05040100) };
        i32x4 lv = { (int)__builtin_amdgcn_perm((u32)d0[1], (u32)d0[0], 0x07060302),
                     (int)__builtin_amdgcn_perm((u32)d0[3], (u32)d0[2], 0x07060302),
                     (int)__builtin_amdgcn_perm((u32)d1[1], (u32)d1[0], 0x07060302),
                     (int)__builtin_amdgcn_perm((u32)d1[3], (u32)d1[2], 0x07060302) };
        ah[mi] = __builtin_bit_cast(bf16x8, hv);
        al[mi] = __builtin_bit_cast(bf16x8, lv);
      }
#pragma unroll
      for (int g = 0; g < 4; ++g) {
        bf16x8 bh = __builtin_bit_cast(bf16x8, whA[g]);
        bf16x8 bl = __builtin_bit_cast(bf16x8, wlA[g]);
#pragma unroll
        for (int mi = 0; mi < 4; ++mi) {
          acc[mi][g] = __builtin_amdgcn_mfma_f32_16x16x32_bf16(ah[mi], bh, acc[mi][g], 0, 0, 0);
          acc[mi][g] = __builtin_amdgcn_mfma_f32_16x16x32_bf16(al[mi], bh, acc[mi][g], 0, 0, 0);
          acc[mi][g] = __builtin_amdgcn_mfma_f32_16x16x32_bf16(ah[mi], bl, acc[mi][g], 0, 0, 0);
        }
      }
    };

    auto nsof = [&](int cc) { return isK64(cc) ? 2 : 4; };

    stage(0, 0);
    {
      const u32* A; int st, kb; bool ish; const u16* Wp; int NK;
      prmA(0, A, st, kb, ish, Wp, NK);
      if (kk < nsof(0)) loadW(Wp, NK, (kb >> 5) + kk, whA, wlA);
    }
    __syncthreads();

    for (int cc = 0; cc < NC; ++cc) {
      int buf = cc & 1;
      bool more = cc + 1 < NC;
      if (more) {
        stage(cc + 1, buf ^ 1);
        const u32* A; int st, kb; bool ish; const u16* Wp; int NK;
        prmA(cc + 1, A, st, kb, ish, Wp, NK);
        if (kk < nsof(cc + 1)) loadW(Wp, NK, (kb >> 5) + kk, whB, wlB);
      }
      if (kk < nsof(cc)) mstep(buf, isK64(cc) ? 64 : 128);
      __syncthreads();
      if (more) {
#pragma unroll
        for (int g = 0; g < 4; ++g) { whA[g] = whB[g]; wlA[g] = wlB[g]; }
      }
    }

    // 4-way K-split reduction through LDS
    float* red = (float*)smem_;
#pragma unroll
    for (int mi = 0; mi < 4; ++mi) {
      if (mi != kk) {
        int slot2 = kk - (kk > mi ? 1 : 0);
        float* base = red + (size_t)(((jh * 4 + mi) * 3 + slot2) * 1024) + lane * 4;
#pragma unroll
        for (int g = 0; g < 4; ++g) *(f32x4*)(base + g * 256) = acc[mi][g];
      }
    }
    __syncthreads();

    f32x4 r[4];
#pragma unroll
    for (int g = 0; g < 4; ++g) r[g] = acc[0][g];
    if (kk == 1) {
#pragma unroll
      for (int g = 0; g < 4; ++g) r[g] = acc[1][g];
    } else if (kk == 2) {
#pragma unroll
      for (int g = 0; g < 4; ++g) r[g] = acc[2][g];
    } else if (kk == 3) {
#pragma unroll
      for (int g = 0; g < 4; ++g) r[g] = acc[3][g];
    }
#pragma unroll
    for (int sl = 0; sl < 3; ++sl) {
      float* base = red + (size_t)(((jh * 4 + kk) * 3 + sl) * 1024) + lane * 4;
#pragma unroll
      for (int g = 0; g < 4; ++g) r[g] += *(const f32x4*)(base + g * 256);
    }

    // epilogue: C/D col = lane&15 -> j, row = qk*4+rr -> batch
    const int   j   = jblk * 32 + jh * 16 + lr;
    const float bi  = bias[j];
    const float bff = bias[512 + j];
    const float bg  = bias[1024 + j];
    const float bo  = bias[1536 + j];
#pragma unroll
    for (int rr = 0; rr < 4; ++rr) {
      int b   = mbase + kk * 16 + qk * 4 + rr;
      int idx = b * 512 + j;
      float iv = sigm(r[0][rr] + bi);
      float fv = sigm(r[1][rr] + bff);
      float gv = tanh_(r[2][rr] + bg);
      float ov = sigm(r[3][rr] + bo);
      float cn = fv * cmem[idx] + iv * gv;
      cmem[idx] = cn;
      float hn = ov * tanh_(cn);
      u16 hh = f2bf(hn);
      u16 hl = f2bf(hn - bf2f(hh));
      hout[idx] = (u32)hh | ((u32)hl << 16);   // write-through -> local L2
    }
  };

  int target = 0;
  u32 *h0r = P.h0a, *h0w = P.h0b, *h1r = P.h1a, *h1w = P.h1b;

  for (int s = 0; s < S_ + PRED - 1; ++s) {
    if (s < S_)
      layer_pass(P.Xp + (size_t)s * F_, S_ * F_, 64, false, P.W0cp,
                 h0r, P.Whh0p, P.b0c, P.c0, h0w);
    else
      layer_pass(h1r, 512, 512, true, P.W0cdp,
                 h0r, P.Whh0p, P.b0ar, P.c0, h0w);
    gbar(target += 32);

    layer_pass(h0w, 512, 512, true, P.Wih1p,
               h1r, P.Whh1p, P.b1c, P.c1, h1w);
    gbar(target += 32);

    // ---- decoder: XCD-local, exclusive (b,f) writes, no atomics ----
    if (s >= S_ - 1) {
      float* outp = P.out + (size_t)(s - (S_ - 1)) * F_;
      float* part = (float*)smem_;
      if (t < 256) {
        int bh = t >> 2, kq = t & 3;
        const u32* hp = h1w + (size_t)(mbase + bh) * 512 + kq * 128;
        const float* wd = P.Wdec + (size_t)(jblk * 4) * 512 + kq * 128;
        float s0 = 0.f, s1 = 0.f, s2 = 0.f, s3 = 0.f;
        for (int g = 0; g < 4; ++g) {
          i32x4 hr[8];
          load8_sc0_wait(hr, hp + g * 32);
#pragma unroll
          for (int q = 0; q < 8; ++q)
#pragma unroll
            for (int e = 0; e < 4; ++e) {
              u32 pk = (u32)hr[q][e];
              float hv = bf2f((u16)(pk & 0xffffu)) + bf2f((u16)(pk >> 16));
              int k = g * 32 + q * 4 + e;
              s0 += hv * wd[k];
              s1 += hv * wd[512 + k];
              s2 += hv * wd[1024 + k];
              s3 += hv * wd[1536 + k];
            }
        }
        part[bh * 16 + kq * 4 + 0] = s0;
        part[bh * 16 + kq * 4 + 1] = s1;
        part[bh * 16 + kq * 4 + 2] = s2;
        part[bh * 16 + kq * 4 + 3] = s3;
      }
      __syncthreads();
      if (t < 256) {
        int bh = t >> 2, f = t & 3;
        float tot = part[bh * 16 + f] + part[bh * 16 + 4 + f] +
                    part[bh * 16 + 8 + f] + part[bh * 16 + 12 + f] +
                    P.bdec[jblk * 4 + f];
        outp[(size_t)(mbase + bh) * (PRED * F_) + jblk * 4 + f] = tot;
      }
      __syncthreads();   // protect smem_ before next layer_pass staging
    }

    u32* tmp;
    tmp = h0r; h0r = h0w; h0w = tmp;
    tmp = h1r; h1r = h1w; h1w = tmp;
  }
}

// ---------------- host orchestration ----------------

extern "C" void kernel_launch(void* const* d_in, const int* in_sizes, int n_in,
                              void* d_out, int out_size, void* d_ws, size_t ws_size,
                              hipStream_t stream) {
  const float* x    = (const float*)d_in[0];
  const float* Wenc = (const float*)d_in[1];
  const float* benc = (const float*)d_in[2];
  const float* Wih0 = (const float*)d_in[3];
  const float* Whh0 = (const float*)d_in[4];
  const float* bih0 = (const float*)d_in[5];
  const float* bhh0 = (const float*)d_in[6];
  const float* Wih1 = (const float*)d_in[7];
  const float* Whh1 = (const float*)d_in[8];
  const float* bih1 = (const float*)d_in[9];
  const float* bhh1 = (const float*)d_in[10];
  const float* Wdec = (const float*)d_in[11];
  const float* bdec = (const float*)d_in[12];

  char* p = (char*)d_ws;
  auto carve = [&](size_t bytes) { char* r = p; p += (bytes + 255) & ~(size_t)255; return r; };
  const size_t NX = (size_t)B_ * S_ * F_;
  const size_t NH = (size_t)B_ * H_;
  const size_t WPK = (size_t)G4 * 512 * 2 * 2;
  u32* Xp     = (u32*)carve(NX * 4);
  float* W0c  = (float*)carve((size_t)G4 * 64 * 4);
  float* W0cd = (float*)carve((size_t)G4 * 512 * 4);
  u16* W0cp   = (u16*)carve((size_t)G4 * 64 * 2 * 2);
  u16* W0cdp  = (u16*)carve(WPK);
  u16* Whh0p  = (u16*)carve(WPK);
  u16* Wih1p  = (u16*)carve(WPK);
  u16* Whh1p  = (u16*)carve(WPK);
  float* b0c  = (float*)carve(G4 * 4);
  float* b0ar = (float*)carve(G4 * 4);
  float* b1c  = (float*)carve(G4 * 4);
  u32* h0a = (u32*)carve(NH * 4);
  u32* h0b = (u32*)carve(NH * 4);
  u32* h1a = (u32*)carve(NH * 4);
  u32* h1b = (u32*)carve(NH * 4);
  float* c0 = (float*)carve(NH * 4);
  float* c1 = (float*)carve(NH * 4);
  u32* xcdctr = (u32*)carve(8 * 64 * 4);
  u32* cnt8   = (u32*)carve(8 * 64 * 4);
  (void)ws_size; (void)n_in; (void)in_sizes;

  hipMemsetAsync(d_out, 0, (size_t)out_size * 4, stream);
  hipMemsetAsync(h0a, 0, NH * 4, stream);
  hipMemsetAsync(h1a, 0, NH * 4, stream);
  hipMemsetAsync(c0, 0, NH * 4, stream);
  hipMemsetAsync(c1, 0, NH * 4, stream);
  hipMemsetAsync(xcdctr, 0, 8 * 64 * 4 * 2, stream);   // xcdctr + cnt8 (contiguous)

  k_splitpack<<<4096, 256, 0, stream>>>(x, Xp, (int)NX);
  k_w0c<<<512, 256, 0, stream>>>(Wih0, Wenc, W0c);
  k_w0cd<<<4096, 256, 0, stream>>>(W0c, Wdec, W0cd);
  k_biases<<<8, 256, 0, stream>>>(Wih0, benc, bih0, bhh0, bih1, bhh1, b0c, b1c);
  k_b0ar<<<8, 256, 0, stream>>>(W0c, bdec, b0c, b0ar);
  k_pack<<<32 * 16, 256, 0, stream>>>(Whh0, 512, Whh0p);
  k_pack<<<32 * 16, 256, 0, stream>>>(Wih1, 512, Wih1p);
  k_pack<<<32 * 16, 256, 0, stream>>>(Whh1, 512, Whh1p);
  k_pack<<<32 * 16, 256, 0, stream>>>(W0cd, 512, W0cdp);
  k_pack<<<32 * 2, 256, 0, stream>>>(W0c, 64, W0cp);

  Params prm;
  prm.Xp = Xp;
  prm.W0cp = W0cp; prm.W0cdp = W0cdp; prm.Whh0p = Whh0p;
  prm.Wih1p = Wih1p; prm.Whh1p = Whh1p;
  prm.b0c = b0c; prm.b0ar = b0ar; prm.b1c = b1c;
  prm.h0a = h0a; prm.h0b = h0b; prm.h1a = h1a; prm.h1b = h1b;
  prm.c0 = c0; prm.c1 = c1;
  prm.Wdec = Wdec; prm.bdec = bdec;
  prm.out = (float*)d_out;
  prm.xcdctr = xcdctr; prm.cnt8 = cnt8;

  void* kargs[] = { &prm };
  hipLaunchCooperativeKernel(reinterpret_cast<void*>(lstm_persist),
                             dim3(NWG), dim3(NTH), kargs, 0, stream);
}